// Round 7
// baseline (493.123 us; speedup 1.0000x reference)
//
#include <hip/hip_runtime.h>
#include <hip/hip_bf16.h>

// Problem constants
constexpr int       DIM        = 128;
constexpr long long CN         = 131073;               // 1 + QUEUE_K
constexpr long long OUT_ELEMS  = 256LL * 131073LL;     // 33554688
constexpr long long PROBS_OFF  = OUT_ELEMS;
constexpr long long MEMOUT_OFF = OUT_ELEMS + 1;
constexpr long long MEM_ELEMS  = 131072LL * 128LL;     // 16777216

constexpr float SCL = 20.60992915555662f;              // log2(e)/0.07

// ws layout (float indices)
constexpr int WS_INVZ  = 0;
constexpr int WS_ELPOS = 16;      // 256 floats
constexpr int WS_KMEAN = 272;     // 64*128 floats
constexpr int WS_ROWP  = 8464;    // 32 slices x 256 floats
constexpr int WS_MEMBF = 16656;   // memory as bf16: ushort[16777216] (32MB), 16B aligned

typedef __attribute__((ext_vector_type(8))) short  short8v;
typedef __attribute__((ext_vector_type(4))) float  f32x4;
typedef __attribute__((ext_vector_type(4), aligned(4))) float f32x4u;  // 4B-aligned vec4

__device__ __forceinline__ unsigned short f2bf(float x) {
  unsigned u = __float_as_uint(x);
  u += 0x7fffu + ((u >> 16) & 1u);   // RNE
  return (unsigned short)(u >> 16);
}

__device__ __forceinline__ short8v pack8(float4 a, float4 b) {
  short8v h;
  h[0] = (short)f2bf(a.x); h[1] = (short)f2bf(a.y);
  h[2] = (short)f2bf(a.z); h[3] = (short)f2bf(a.w);
  h[4] = (short)f2bf(b.x); h[5] = (short)f2bf(b.y);
  h[6] = (short)f2bf(b.z); h[7] = (short)f2bf(b.w);
  return h;
}

// Small prep: k_mean (32 blocks), l_pos (64 blocks), zero rowp (4 blocks)
__global__ __launch_bounds__(256) void k_prep(const float* __restrict__ q,
                                              const float* __restrict__ k,
                                              float* __restrict__ ws) {
  const int b = blockIdx.x, t = threadIdx.x;
  if (b < 32) {                        // k_mean per video
    int j = b * 256 + t;
    int v = j >> 7, d = j & 127;
    ws[WS_KMEAN + j] = 0.25f * (k[v*128+d] + k[(v+64)*128+d] +
                                k[(v+128)*128+d] + k[(v+192)*128+d]);
  } else if (b < 96) {                 // exp(l_pos/T): one wave per row
    int row = (b - 32) * 4 + (t >> 6);
    int lane = t & 63;
    int vid = row & 63;
    float2 qv = ((const float2*)(q + row * DIM))[lane];
    float2 kr = ((const float2*)(k + row * DIM))[lane];
    float s0 = -kr.x, s1 = -kr.y;
    #pragma unroll
    for (int c = 0; c < 4; ++c) {
      float2 kc = ((const float2*)(k + (vid + c * 64) * DIM))[lane];
      s0 += kc.x; s1 += kc.y;
    }
    float acc = qv.x * s0 + qv.y * s1;
    #pragma unroll
    for (int off = 1; off < 64; off <<= 1) acc += __shfl_xor(acc, off, 64);
    if (lane == 0) ws[WS_ELPOS + row] = exp2f(acc * (1.f / 3.f) * SCL);
  } else {                             // zero rowp (32*256 floats)
    int i = (b - 96) * 2048 + t * 8;
    float4 z = {0.f, 0.f, 0.f, 0.f};
    *(float4*)(ws + WS_ROWP + i)     = z;
    *(float4*)(ws + WS_ROWP + i + 4) = z;
  }
}

// Pass A: read memv f32 once: MFMA row-sums of exp + persist bf16 copy + bank-copy (L2-warm).
// grid 1024, NT=4 (128 memory-rows per block).
template<int NT>
__global__ __launch_bounds__(256, 4) void k_gemmA(const float* __restrict__ memv,
                                                  const float* __restrict__ q,
                                                  unsigned short* __restrict__ membf,
                                                  float* __restrict__ ws,
                                                  float* __restrict__ out) {
  const int t = threadIdx.x, lane = t & 63, wave = t >> 6;
  const int g = lane >> 4, nlo = lane & 15;
  // XCD-chunked: hw bid%8 = XCD; each XCD gets a contiguous 128-block (16K-col) span.
  const int logical = (blockIdx.x & 7) * 128 + (blockIdx.x >> 3);

  // q fragments f32 -> bf16 in-reg (q 128KB, L2/L3-resident)
  short8v af[4][4];                            // [ks][mf]
  #pragma unroll
  for (int ks = 0; ks < 4; ++ks)
    #pragma unroll
    for (int mf = 0; mf < 4; ++mf) {
      const float4* src = (const float4*)(q + (wave*64 + mf*16 + nlo)*DIM + ks*32 + g*8);
      af[ks][mf] = pack8(src[0], src[1]);
    }

  float sums[4][4];
  #pragma unroll
  for (int mf = 0; mf < 4; ++mf)
    #pragma unroll
    for (int r = 0; r < 4; ++r) sums[mf][r] = 0.f;

  for (int it = 0; it < NT; ++it) {
    const long long n0 = ((long long)logical * NT + it) * 32;
    f32x4 acc[4][2];
    f32x4 zero = {0.f, 0.f, 0.f, 0.f};
    #pragma unroll
    for (int mf = 0; mf < 4; ++mf) { acc[mf][0] = zero; acc[mf][1] = zero; }

    #pragma unroll
    for (int ks = 0; ks < 4; ++ks) {
      #pragma unroll
      for (int nf = 0; nf < 2; ++nf) {
        const long long off = (n0 + nf*16 + nlo) * DIM + ks*32 + g*8;
        const float4* src = (const float4*)(memv + off);
        short8v bfr = pack8(src[0], src[1]);
        if (wave == ks)                          // each wave persists one ks-slice
          *(short8v*)(membf + off) = bfr;
        #pragma unroll
        for (int mf = 0; mf < 4; ++mf)
          acc[mf][nf] = __builtin_amdgcn_mfma_f32_16x16x32_bf16(af[ks][mf], bfr, acc[mf][nf], 0, 0, 0);
      }
    }

    #pragma unroll
    for (int mf = 0; mf < 4; ++mf)
      #pragma unroll
      for (int r = 0; r < 4; ++r)
        sums[mf][r] += exp2f(acc[mf][0][r] * SCL) + exp2f(acc[mf][1][r] * SCL);
  }

  {
    float* rowp = ws + WS_ROWP + (blockIdx.x & 31) * 256;
    #pragma unroll
    for (int mf = 0; mf < 4; ++mf) {
      #pragma unroll
      for (int r = 0; r < 4; ++r) {
        float s = sums[mf][r];
        s += __shfl_xor(s, 1, 16);
        s += __shfl_xor(s, 2, 16);
        s += __shfl_xor(s, 4, 16);
        s += __shfl_xor(s, 8, 16);
        if (nlo == 0) atomicAdd(&rowp[wave*64 + mf*16 + g*4 + r], s);  // D: row=4g+r
      }
    }
  }

  // ---- bank-copy of this block's memv range (reads L2-warm), nontemporal writes ----
  {
    float* dst = out + MEMOUT_OFF;     // dst groups at base=3+4j are 16B-aligned
    const float* km = ws + WS_KMEAN;   // written by k_prep (previous dispatch, coherent)
    if (logical == 0 && t == 0) {      // scalar edges
      dst[0] = km[0]; dst[1] = km[1]; dst[2] = km[2];
      dst[MEM_ELEMS - 1] = memv[MEM_ELEMS - 1];
    }
    const long long j0 = (long long)logical * 4096;
    #pragma unroll
    for (int i = 0; i < 16; ++i) {
      long long j = j0 + i*256 + t;
      if (j < 4194303LL) {
        long long base = 3 + j*4;
        f32x4u v;
        if (base + 4 <= 8192) {          // kmean region
          v = *(const f32x4u*)(km + base);
        } else if (base >= 8192) {
          v = *(const f32x4u*)(memv + base);
        } else {                         // straddling group (base==8191)
          float tmp[4];
          #pragma unroll
          for (int e = 0; e < 4; ++e) {
            long long idx = base + e;
            tmp[e] = (idx < 8192) ? km[idx] : memv[idx];
          }
          v.x = tmp[0]; v.y = tmp[1]; v.z = tmp[2]; v.w = tmp[3];
        }
        __builtin_nontemporal_store(v, (f32x4u*)(dst + base));
      }
    }
  }
}

__global__ void k_fin(float* __restrict__ ws, float* __restrict__ out) {
  __shared__ float s_tot[256];
  __shared__ float s_pr[256];
  __shared__ float sh_invZ;
  int t = threadIdx.x;
  float s = ws[WS_ELPOS + t];
  float rs = s;
  for (int sl = 0; sl < 32; ++sl) rs += ws[WS_ROWP + sl * 256 + t];
  s_tot[t] = rs;
  s_pr[t] = s / rs;                     // scale-invariant
  __syncthreads();
  for (int off = 128; off > 0; off >>= 1) {
    if (t < off) { s_tot[t] += s_tot[t + off]; s_pr[t] += s_pr[t + off]; }
    __syncthreads();
  }
  if (t == 0) {
    double Z = (double)s_tot[0] * (1000000.0 / (256.0 * 131073.0));
    float invZ = (float)(1.0 / Z);
    ws[WS_INVZ] = invZ;
    sh_invZ = invZ;
    out[PROBS_OFF] = s_pr[0] * (1.f / 256.f);
  }
  __syncthreads();
  out[(long long)t * CN] = s * sh_invZ;
}

// Pass B: bf16 tiles from membf (L2/L3-warm), write out[:,1:] nontemporal.
// grid 1024, NT=4, XCD-chunked swizzle.
template<int NT>
__global__ __launch_bounds__(256, 4) void k_gemmB(const unsigned short* __restrict__ membf,
                                                  const float* __restrict__ q,
                                                  const float* __restrict__ ws,
                                                  float* __restrict__ out) {
  const int t = threadIdx.x, lane = t & 63, wave = t >> 6;
  const int g = lane >> 4, nlo = lane & 15;
  const float invZ = ws[WS_INVZ];
  const int logical = (blockIdx.x & 7) * 128 + (blockIdx.x >> 3);

  short8v af[4][4];
  #pragma unroll
  for (int ks = 0; ks < 4; ++ks)
    #pragma unroll
    for (int mf = 0; mf < 4; ++mf) {
      const float4* src = (const float4*)(q + (wave*64 + mf*16 + nlo)*DIM + ks*32 + g*8);
      af[ks][mf] = pack8(src[0], src[1]);
    }

  for (int it = 0; it < NT; ++it) {
    const long long n0 = ((long long)logical * NT + it) * 32;
    f32x4 acc[4][2];
    f32x4 zero = {0.f, 0.f, 0.f, 0.f};
    #pragma unroll
    for (int mf = 0; mf < 4; ++mf) { acc[mf][0] = zero; acc[mf][1] = zero; }

    #pragma unroll
    for (int ks = 0; ks < 4; ++ks) {
      short8v b0 = *(const short8v*)(membf + (n0 + nlo)      * DIM + ks*32 + g*8);
      short8v b1 = *(const short8v*)(membf + (n0 + 16 + nlo) * DIM + ks*32 + g*8);
      #pragma unroll
      for (int mf = 0; mf < 4; ++mf) {
        acc[mf][0] = __builtin_amdgcn_mfma_f32_16x16x32_bf16(af[ks][mf], b0, acc[mf][0], 0, 0, 0);
        acc[mf][1] = __builtin_amdgcn_mfma_f32_16x16x32_bf16(af[ks][mf], b1, acc[mf][1], 0, 0, 0);
      }
    }

    #pragma unroll
    for (int mf = 0; mf < 4; ++mf) {
      #pragma unroll
      for (int r = 0; r < 4; ++r) {
        const long long base = (long long)(wave*64 + mf*16 + g*4 + r) * CN + 1 + nlo + n0;
        __builtin_nontemporal_store(exp2f(acc[mf][0][r] * SCL) * invZ, out + base);
        __builtin_nontemporal_store(exp2f(acc[mf][1][r] * SCL) * invZ, out + base + 16);
      }
    }
  }
}

extern "C" void kernel_launch(void* const* d_in, const int* in_sizes, int n_in,
                              void* d_out, int out_size, void* d_ws, size_t ws_size,
                              hipStream_t stream) {
  (void)in_sizes; (void)n_in; (void)out_size; (void)ws_size;
  const float* q    = (const float*)d_in[0];
  const float* k    = (const float*)d_in[1];
  const float* memv = (const float*)d_in[2];
  float* out = (float*)d_out;
  float* ws  = (float*)d_ws;
  unsigned short* membf = (unsigned short*)(ws + WS_MEMBF);

  hipLaunchKernelGGL(k_prep, dim3(100), dim3(256), 0, stream, q, k, ws);
  hipLaunchKernelGGL((k_gemmA<4>), dim3(1024), dim3(256), 0, stream, memv, q, membf, ws, out);
  hipLaunchKernelGGL(k_fin,  dim3(1),   dim3(256), 0, stream, ws, out);
  hipLaunchKernelGGL((k_gemmB<4>), dim3(1024), dim3(256), 0, stream, membf, q, ws, out);
}

// Round 8
// 480.329 us; speedup vs baseline: 1.0266x; 1.0266x over previous
//
#include <hip/hip_runtime.h>
#include <hip/hip_bf16.h>

// Problem constants
constexpr int       DIM        = 128;
constexpr long long CN         = 131073;               // 1 + QUEUE_K
constexpr long long OUT_ELEMS  = 256LL * 131073LL;     // 33554688
constexpr long long PROBS_OFF  = OUT_ELEMS;
constexpr long long MEMOUT_OFF = OUT_ELEMS + 1;
constexpr long long MEM_ELEMS  = 131072LL * 128LL;     // 16777216

constexpr float SCL = 20.60992915555662f;              // log2(e)/0.07

// ws layout (float indices)
constexpr int WS_INVZ  = 0;
constexpr int WS_ELPOS = 16;      // 256 floats
constexpr int WS_KMEAN = 272;     // 64*128 floats
constexpr int WS_ROWP  = 8464;    // 32 slices x 256 floats
constexpr int WS_MEMBF = 16656;   // memory as bf16: ushort[16777216] (32MB), 16B aligned

typedef __attribute__((ext_vector_type(8))) short  short8v;
typedef __attribute__((ext_vector_type(4))) float  f32x4;
typedef __attribute__((ext_vector_type(4), aligned(4))) float f32x4u;  // 4B-aligned vec4

__device__ __forceinline__ unsigned short f2bf(float x) {
  unsigned u = __float_as_uint(x);
  u += 0x7fffu + ((u >> 16) & 1u);   // RNE
  return (unsigned short)(u >> 16);
}

__device__ __forceinline__ short8v pack8(float4 a, float4 b) {
  short8v h;
  h[0] = (short)f2bf(a.x); h[1] = (short)f2bf(a.y);
  h[2] = (short)f2bf(a.z); h[3] = (short)f2bf(a.w);
  h[4] = (short)f2bf(b.x); h[5] = (short)f2bf(b.y);
  h[6] = (short)f2bf(b.z); h[7] = (short)f2bf(b.w);
  return h;
}

// Small prep: k_mean (32 blocks), l_pos (64 blocks), zero rowp (4 blocks)
__global__ __launch_bounds__(256) void k_prep(const float* __restrict__ q,
                                              const float* __restrict__ k,
                                              float* __restrict__ ws) {
  const int b = blockIdx.x, t = threadIdx.x;
  if (b < 32) {                        // k_mean per video
    int j = b * 256 + t;
    int v = j >> 7, d = j & 127;
    ws[WS_KMEAN + j] = 0.25f * (k[v*128+d] + k[(v+64)*128+d] +
                                k[(v+128)*128+d] + k[(v+192)*128+d]);
  } else if (b < 96) {                 // exp(l_pos/T): one wave per row
    int row = (b - 32) * 4 + (t >> 6);
    int lane = t & 63;
    int vid = row & 63;
    float2 qv = ((const float2*)(q + row * DIM))[lane];
    float2 kr = ((const float2*)(k + row * DIM))[lane];
    float s0 = -kr.x, s1 = -kr.y;
    #pragma unroll
    for (int c = 0; c < 4; ++c) {
      float2 kc = ((const float2*)(k + (vid + c * 64) * DIM))[lane];
      s0 += kc.x; s1 += kc.y;
    }
    float acc = qv.x * s0 + qv.y * s1;
    #pragma unroll
    for (int off = 1; off < 64; off <<= 1) acc += __shfl_xor(acc, off, 64);
    if (lane == 0) ws[WS_ELPOS + row] = exp2f(acc * (1.f / 3.f) * SCL);
  } else {                             // zero rowp (32*256 floats)
    int i = (b - 96) * 2048 + t * 8;
    float4 z = {0.f, 0.f, 0.f, 0.f};
    *(float4*)(ws + WS_ROWP + i)     = z;
    *(float4*)(ws + WS_ROWP + i + 4) = z;
  }
}

// Pass A: read memv f32 once: MFMA row-sums of exp + persist bf16 copy + bank-copy (L2-warm).
// grid 2048, NT=2 (64 memory-rows per block). No nontemporal: let L2 merge.
template<int NT, int GRID>
__global__ __launch_bounds__(256, 4) void k_gemmA(const float* __restrict__ memv,
                                                  const float* __restrict__ q,
                                                  unsigned short* __restrict__ membf,
                                                  float* __restrict__ ws,
                                                  float* __restrict__ out) {
  const int t = threadIdx.x, lane = t & 63, wave = t >> 6;
  const int g = lane >> 4, nlo = lane & 15;
  // XCD-chunked: hw bid%8 = XCD; each XCD gets a contiguous GRID/8-block span.
  const int logical = (blockIdx.x & 7) * (GRID / 8) + (blockIdx.x >> 3);

  // q fragments f32 -> bf16 in-reg (q 128KB, L2/L3-resident)
  short8v af[4][4];                            // [ks][mf]
  #pragma unroll
  for (int ks = 0; ks < 4; ++ks)
    #pragma unroll
    for (int mf = 0; mf < 4; ++mf) {
      const float4* src = (const float4*)(q + (wave*64 + mf*16 + nlo)*DIM + ks*32 + g*8);
      af[ks][mf] = pack8(src[0], src[1]);
    }

  float sums[4][4];
  #pragma unroll
  for (int mf = 0; mf < 4; ++mf)
    #pragma unroll
    for (int r = 0; r < 4; ++r) sums[mf][r] = 0.f;

  for (int it = 0; it < NT; ++it) {
    const long long n0 = ((long long)logical * NT + it) * 32;
    f32x4 acc[4][2];
    f32x4 zero = {0.f, 0.f, 0.f, 0.f};
    #pragma unroll
    for (int mf = 0; mf < 4; ++mf) { acc[mf][0] = zero; acc[mf][1] = zero; }

    #pragma unroll
    for (int ks = 0; ks < 4; ++ks) {
      #pragma unroll
      for (int nf = 0; nf < 2; ++nf) {
        const long long off = (n0 + nf*16 + nlo) * DIM + ks*32 + g*8;
        const float4* src = (const float4*)(memv + off);
        short8v bfr = pack8(src[0], src[1]);
        if (wave == ks)                          // each wave persists one ks-slice
          *(short8v*)(membf + off) = bfr;
        #pragma unroll
        for (int mf = 0; mf < 4; ++mf)
          acc[mf][nf] = __builtin_amdgcn_mfma_f32_16x16x32_bf16(af[ks][mf], bfr, acc[mf][nf], 0, 0, 0);
      }
    }

    #pragma unroll
    for (int mf = 0; mf < 4; ++mf)
      #pragma unroll
      for (int r = 0; r < 4; ++r)
        sums[mf][r] += exp2f(acc[mf][0][r] * SCL) + exp2f(acc[mf][1][r] * SCL);
  }

  {
    float* rowp = ws + WS_ROWP + (blockIdx.x & 31) * 256;
    #pragma unroll
    for (int mf = 0; mf < 4; ++mf) {
      #pragma unroll
      for (int r = 0; r < 4; ++r) {
        float s = sums[mf][r];
        s += __shfl_xor(s, 1, 16);
        s += __shfl_xor(s, 2, 16);
        s += __shfl_xor(s, 4, 16);
        s += __shfl_xor(s, 8, 16);
        if (nlo == 0) atomicAdd(&rowp[wave*64 + mf*16 + g*4 + r], s);  // D: row=4g+r
      }
    }
  }

  // ---- bank-copy of this block's memv range (reads L2-warm) ----
  {
    float* dst = out + MEMOUT_OFF;     // dst groups at base=3+4j are 16B-aligned
    const float* km = ws + WS_KMEAN;   // written by k_prep (previous dispatch, coherent)
    if (logical == 0 && t == 0) {      // scalar edges
      dst[0] = km[0]; dst[1] = km[1]; dst[2] = km[2];
      dst[MEM_ELEMS - 1] = memv[MEM_ELEMS - 1];
    }
    constexpr int GROUPS_PER_BLOCK = (NT * 32 * DIM) / 4;          // = 2048 for NT=2
    constexpr int ITERS = GROUPS_PER_BLOCK / 256;                  // = 8
    const long long j0 = (long long)logical * GROUPS_PER_BLOCK;
    #pragma unroll
    for (int i = 0; i < ITERS; ++i) {
      long long j = j0 + i*256 + t;
      if (j < (MEM_ELEMS - 4) / 4) {
        long long base = 3 + j*4;
        f32x4u v;
        if (base + 4 <= 8192) {          // kmean region
          v = *(const f32x4u*)(km + base);
        } else if (base >= 8192) {
          v = *(const f32x4u*)(memv + base);
        } else {                         // straddling group (base==8191)
          float tmp[4];
          #pragma unroll
          for (int e = 0; e < 4; ++e) {
            long long idx = base + e;
            tmp[e] = (idx < 8192) ? km[idx] : memv[idx];
          }
          v.x = tmp[0]; v.y = tmp[1]; v.z = tmp[2]; v.w = tmp[3];
        }
        *(f32x4u*)(dst + base) = v;
      }
    }
  }
}

__global__ void k_fin(float* __restrict__ ws, float* __restrict__ out) {
  __shared__ float s_tot[256];
  __shared__ float s_pr[256];
  __shared__ float sh_invZ;
  int t = threadIdx.x;
  float s = ws[WS_ELPOS + t];
  float rs = s;
  for (int sl = 0; sl < 32; ++sl) rs += ws[WS_ROWP + sl * 256 + t];
  s_tot[t] = rs;
  s_pr[t] = s / rs;                     // scale-invariant
  __syncthreads();
  for (int off = 128; off > 0; off >>= 1) {
    if (t < off) { s_tot[t] += s_tot[t + off]; s_pr[t] += s_pr[t + off]; }
    __syncthreads();
  }
  if (t == 0) {
    double Z = (double)s_tot[0] * (1000000.0 / (256.0 * 131073.0));
    float invZ = (float)(1.0 / Z);
    ws[WS_INVZ] = invZ;
    sh_invZ = invZ;
    out[PROBS_OFF] = s_pr[0] * (1.f / 256.f);
  }
  __syncthreads();
  out[(long long)t * CN] = s * sh_invZ;
}

// Pass B: bf16 tiles from membf (L2/L3-warm), write out[:,1:] (regular stores; L2 merges).
// grid 2048, NT=2, XCD-chunked swizzle.
template<int NT, int GRID>
__global__ __launch_bounds__(256, 4) void k_gemmB(const unsigned short* __restrict__ membf,
                                                  const float* __restrict__ q,
                                                  const float* __restrict__ ws,
                                                  float* __restrict__ out) {
  const int t = threadIdx.x, lane = t & 63, wave = t >> 6;
  const int g = lane >> 4, nlo = lane & 15;
  const float invZ = ws[WS_INVZ];
  const int logical = (blockIdx.x & 7) * (GRID / 8) + (blockIdx.x >> 3);

  short8v af[4][4];
  #pragma unroll
  for (int ks = 0; ks < 4; ++ks)
    #pragma unroll
    for (int mf = 0; mf < 4; ++mf) {
      const float4* src = (const float4*)(q + (wave*64 + mf*16 + nlo)*DIM + ks*32 + g*8);
      af[ks][mf] = pack8(src[0], src[1]);
    }

  for (int it = 0; it < NT; ++it) {
    const long long n0 = ((long long)logical * NT + it) * 32;
    f32x4 acc[4][2];
    f32x4 zero = {0.f, 0.f, 0.f, 0.f};
    #pragma unroll
    for (int mf = 0; mf < 4; ++mf) { acc[mf][0] = zero; acc[mf][1] = zero; }

    #pragma unroll
    for (int ks = 0; ks < 4; ++ks) {
      short8v b0 = *(const short8v*)(membf + (n0 + nlo)      * DIM + ks*32 + g*8);
      short8v b1 = *(const short8v*)(membf + (n0 + 16 + nlo) * DIM + ks*32 + g*8);
      #pragma unroll
      for (int mf = 0; mf < 4; ++mf) {
        acc[mf][0] = __builtin_amdgcn_mfma_f32_16x16x32_bf16(af[ks][mf], b0, acc[mf][0], 0, 0, 0);
        acc[mf][1] = __builtin_amdgcn_mfma_f32_16x16x32_bf16(af[ks][mf], b1, acc[mf][1], 0, 0, 0);
      }
    }

    #pragma unroll
    for (int mf = 0; mf < 4; ++mf) {
      #pragma unroll
      for (int r = 0; r < 4; ++r) {
        const long long base = (long long)(wave*64 + mf*16 + g*4 + r) * CN + 1 + nlo + n0;
        out[base]      = exp2f(acc[mf][0][r] * SCL) * invZ;
        out[base + 16] = exp2f(acc[mf][1][r] * SCL) * invZ;
      }
    }
  }
}

extern "C" void kernel_launch(void* const* d_in, const int* in_sizes, int n_in,
                              void* d_out, int out_size, void* d_ws, size_t ws_size,
                              hipStream_t stream) {
  (void)in_sizes; (void)n_in; (void)out_size; (void)ws_size;
  const float* q    = (const float*)d_in[0];
  const float* k    = (const float*)d_in[1];
  const float* memv = (const float*)d_in[2];
  float* out = (float*)d_out;
  float* ws  = (float*)d_ws;
  unsigned short* membf = (unsigned short*)(ws + WS_MEMBF);

  hipLaunchKernelGGL(k_prep, dim3(100), dim3(256), 0, stream, q, k, ws);
  hipLaunchKernelGGL((k_gemmA<2, 2048>), dim3(2048), dim3(256), 0, stream, memv, q, membf, ws, out);
  hipLaunchKernelGGL(k_fin,  dim3(1),   dim3(256), 0, stream, ws, out);
  hipLaunchKernelGGL((k_gemmB<2, 2048>), dim3(2048), dim3(256), 0, stream, membf, q, ws, out);
}